// Round 7
// baseline (200.732 us; speedup 1.0000x reference)
//
#include <hip/hip_runtime.h>

#define DIN 1024
#define LSEQ 2048

typedef _Float16 f16;
typedef _Float16 half8 __attribute__((ext_vector_type(8)));
typedef float floatx4 __attribute__((ext_vector_type(4)));

__device__ __forceinline__ void async_ld16(const void* g, void* l) {
  __builtin_amdgcn_global_load_lds(
      (const __attribute__((address_space(1))) void*)g,
      (__attribute__((address_space(3))) void*)l, 16, 0, 0);
}

__device__ __forceinline__ float fast_exp2(float x) {
#if __has_builtin(__builtin_amdgcn_exp2f)
  return __builtin_amdgcn_exp2f(x);
#else
  return exp2f(x);
#endif
}

__device__ __forceinline__ unsigned int pack2_f16(float a, float b) {
#if __has_builtin(__builtin_amdgcn_cvt_pkrtz)
  typedef __fp16 fp16x2 __attribute__((ext_vector_type(2)));
  fp16x2 h = __builtin_amdgcn_cvt_pkrtz(a, b);
  return __builtin_bit_cast(unsigned int, h);
#else
  union { f16 h[2]; unsigned int u; } pk;
  pk.h[0] = (f16)a; pk.h[1] = (f16)b;
  return pk.u;
#endif
}

// ---------------- Kernel 1: W [k][n] fp32 -> Wt [n][k] fp16 ----------------
__global__ void __launch_bounds__(256) kwt(const float* __restrict__ wq,
                                           const float* __restrict__ wk,
                                           const float* __restrict__ wv,
                                           f16* __restrict__ wqt,
                                           f16* __restrict__ wkt,
                                           f16* __restrict__ wvt) {
  __shared__ float t[32][33];
  const float* src = blockIdx.z == 0 ? wq : (blockIdx.z == 1 ? wk : wv);
  f16* dst = blockIdx.z == 0 ? wqt : (blockIdx.z == 1 ? wkt : wvt);
  int k0 = blockIdx.x * 32, n0 = blockIdx.y * 32;
  int tx = threadIdx.x, ty = threadIdx.y;  // (32,8)
#pragma unroll
  for (int r = 0; r < 4; ++r)
    t[ty + r * 8][tx] = src[(k0 + ty + r * 8) * DIN + n0 + tx];
  __syncthreads();
#pragma unroll
  for (int r = 0; r < 4; ++r)
    dst[(n0 + ty + r * 8) * DIN + k0 + tx] = (f16)t[tx][ty + r * 8];
}

// ------------- Kernel 2: C = X(4096x1024) @ W -> Q/K fp16, V^T fp16 --------
// 128x128 tile, BK=64, 4 waves (2x2), mfma_f32_16x16x32_f16.
// z=0: Q (pre-scaled by 1/sqrt(64)*log2(e)), [bh][l][64]
// z=1: K, [bh][l][64]
// z=2: V stored TRANSPOSED [bh][64 d][2048 l] via LDS transpose epilogue
//      (replaces the old separate kvt kernel).
__global__ void __launch_bounds__(256) kproj(const float* __restrict__ xq,
                                             const float* __restrict__ xk,
                                             const f16* __restrict__ wqt,
                                             const f16* __restrict__ wkt,
                                             const f16* __restrict__ wvt,
                                             f16* __restrict__ qb,
                                             f16* __restrict__ kb,
                                             f16* __restrict__ vtb) {
  __shared__ __align__(16) char smem[34816];  // As 16K | Bs 16K ; z=2 epilogue
  char* As = smem;                            // overlays [128 n][272B] f16^T
  char* Bs = smem + 16384;
  const float* X;
  const f16* W;
  int z = blockIdx.z;
  if (z == 0) { X = xq; W = wqt; }
  else if (z == 1) { X = xk; W = wkt; }
  else { X = xk; W = wvt; }
  float oscale = (z == 0) ? 0.18033688011112042f : 1.0f;  // SC only for Q
  int m0 = blockIdx.y * 128, n0 = blockIdx.x * 128;
  int tid = threadIdx.x, lane = tid & 63, wid = tid >> 6;
  int wm = wid >> 1, wn = wid & 1;
  int c15 = lane & 15, g = lane >> 4;
  int l8 = lane >> 3, l7 = lane & 7;
  int kk = 8 * (l7 ^ l8);  // pre-swizzled global k-offset for linear LDS dest
  int swz = (c15 & 7) << 4;
  floatx4 acc[4][4] = {};

  for (int kt = 0; kt < 16; ++kt) {
    int k0 = kt * 64;
#pragma unroll
    for (int cc = 0; cc < 4; ++cc) {
      int c = wid * 4 + cc;
      async_ld16(&W[(n0 + c * 8 + l8) * DIN + k0 + kk], Bs + c * 1024);
    }
    {
      int q = tid & 15;
#pragma unroll
      for (int p = 0; p < 8; ++p) {
        int row = p * 16 + (tid >> 4);
        const float4 v = *(const float4*)&X[(m0 + row) * DIN + k0 + q * 4];
        union { unsigned int u[2]; uint2 v2; } pk;
        pk.u[0] = pack2_f16(v.x, v.y);
        pk.u[1] = pack2_f16(v.z, v.w);
        *(uint2*)(As + row * 128 + ((q * 8) ^ ((row & 7) << 4))) = pk.v2;
      }
    }
    __syncthreads();
#pragma unroll
    for (int ks = 0; ks < 2; ++ks) {
      int koff = (ks * 64 + g * 16) ^ swz;
      half8 af[4], bf[4];
#pragma unroll
      for (int i = 0; i < 4; ++i)
        af[i] = *(const half8*)(As + (wm * 64 + i * 16 + c15) * 128 + koff);
#pragma unroll
      for (int j = 0; j < 4; ++j)
        bf[j] = *(const half8*)(Bs + (wn * 64 + j * 16 + c15) * 128 + koff);
#pragma unroll
      for (int i = 0; i < 4; ++i)
#pragma unroll
        for (int j = 0; j < 4; ++j)
          acc[i][j] = __builtin_amdgcn_mfma_f32_16x16x32_f16(af[i], bf[j], acc[i][j], 0, 0, 0);
    }
    __syncthreads();
  }

  if (z != 2) {
    f16* dst = (z == 0) ? qb : kb;
#pragma unroll
    for (int i = 0; i < 4; ++i) {
      int mrow = m0 + wm * 64 + i * 16 + 4 * g;
#pragma unroll
      for (int j = 0; j < 4; ++j) {
        int n = n0 + wn * 64 + j * 16 + c15;
        int h = n >> 6, d = n & 63;
#pragma unroll
        for (int r = 0; r < 4; ++r) {
          int m = mrow + r;
          int b = m >> 11, lrow = m & 2047;
          dst[(((b << 4) + h) * 2048 + lrow) * 64 + d] = (f16)(acc[i][j][r] * oscale);
        }
      }
    }
  } else {
    // V^T epilogue: stash C^T as f16 in LDS [128 n][272B], store coalesced
    // rows of vtb[bh][d][l]. (Last loop barrier freed As/Bs.)
#pragma unroll
    for (int i = 0; i < 4; ++i) {
      int mb = (wm * 64 + i * 16 + 4 * g) * 2;  // byte offset of 4 m-elems
#pragma unroll
      for (int j = 0; j < 4; ++j) {
        int nl = wn * 64 + j * 16 + c15;
        union { unsigned int u[2]; uint2 v; } pk;
        pk.u[0] = pack2_f16(acc[i][j][0], acc[i][j][1]);
        pk.u[1] = pack2_f16(acc[i][j][2], acc[i][j][3]);
        *(uint2*)(smem + nl * 272 + mb) = pk.v;
      }
    }
    __syncthreads();
    int rowp = tid >> 1, halfp = tid & 1;
    int n = n0 + rowp, h = n >> 6, d = n & 63;
    int b = m0 >> 11, lbase = m0 & 2047;
    f16* dstp = vtb + (((size_t)b * 16 + h) * 64 + d) * 2048 + lbase + halfp * 64;
    const char* srcl = smem + rowp * 272 + halfp * 128;
#pragma unroll
    for (int u = 0; u < 8; ++u)
      *(uint4*)(dstp + u * 8) = *(const uint4*)(srcl + u * 16);
  }
}

// --------------------- Kernel 3: flash attention ---------------------------
// 64 q/block (16/wave), KV tile 64. K in LDS (double-buffered, prefetched
// via global_load_lds); V read DIRECTLY from global per lane (L2-resident:
// 4 heads/XCD = 2MB in 4MB L2; g0..g3 read consecutive 16B of one d-row ->
// full 64B lines; latency hides under QK+softmax). LDS = 25KB -> 4 blocks/CU
// (16 waves) vs R4's 3. Shift-free exp2-domain softmax.
__global__ void __launch_bounds__(256, 4) kattn(const f16* __restrict__ qb,
                                                const f16* __restrict__ kbuf,
                                                const f16* __restrict__ vt,
                                                float* __restrict__ out) {
  // [0,16384): K double buffer (buf*8192)
  // [16384, 25088): per-wave P strips (4 x 16q x 136B); Q staging overlay
  __shared__ __align__(16) char smem[25088];
  char* Qs = smem + 16384;
  float* Ot = (float*)smem;  // epilogue overlay [64][68] f32 = 17408B

  // XCD swizzle: 4 heads per XCD -> K/V working set 2MB fits 4MB L2.
  int id = blockIdx.x;
  int wi = id >> 3;
  int bh = ((id & 7) << 2) | (wi >> 5);
  int q0 = (wi & 31) << 6;

  int tid = threadIdx.x, lane = tid & 63, w = tid >> 6;
  int c15 = lane & 15, g = lane >> 4;
  int l8 = lane >> 3, l7 = lane & 7;
  int kk = 8 * (l7 ^ l8);
  int swz = (c15 & 7) << 4;

  const f16* kbase = kbuf + (size_t)bh * 2048 * 64;
  const f16* vbase = vt + (size_t)bh * 64 * 2048;

  auto stageK = [&](int buf, int kv0) {
#pragma unroll
    for (int cc = 0; cc < 2; ++cc) {
      int c = w * 2 + cc;
      async_ld16(&kbase[(kv0 + c * 8 + l8) * 64 + kk], smem + buf * 8192 + c * 1024);
    }
  };

  // prologue: Q (8KB) + K tile0
#pragma unroll
  for (int cc = 0; cc < 2; ++cc) {
    int c = w * 2 + cc;
    async_ld16(&qb[((size_t)bh * 2048 + q0 + c * 8 + l8) * 64 + kk],
               Qs + c * 1024);
  }
  stageK(0, 0);
  __syncthreads();
  half8 qf[2];
#pragma unroll
  for (int ks = 0; ks < 2; ++ks)
    qf[ks] = *(const half8*)(Qs + (w * 16 + c15) * 128 + ((ks * 64 + g * 16) ^ swz));
  __syncthreads();  // all qf reads done before anyone writes P over Qs

  float lsum = 0.f;
  floatx4 oacc[4] = {};
  char* Pw = smem + 16384 + w * 2176 + c15 * 136;

  int buf = 0;
  for (int t = 0; t < 32; ++t) {
    int kv0 = t * 64;
    if (t < 31) stageK(buf ^ 1, kv0 + 64);  // prefetch next K tile

    // V fragments for THIS tile direct from global (L2); latency hides
    // under QK + softmax below.
    half8 vfr[2][4];
#pragma unroll
    for (int kb = 0; kb < 2; ++kb)
#pragma unroll
      for (int df = 0; df < 4; ++df)
        vfr[kb][df] = *(const half8*)&vbase[(size_t)(16 * df + c15) * 2048 +
                                            kv0 + kb * 32 + 8 * g];

    const char* Ks = smem + buf * 8192;

    // S^T = K @ Q^T : rows kv (16i+4g+r), col q (w*16+c15); exp2 domain
    floatx4 st[4] = {};
    __builtin_amdgcn_s_setprio(1);
#pragma unroll
    for (int ks = 0; ks < 2; ++ks) {
      int koff = (ks * 64 + g * 16) ^ swz;
#pragma unroll
      for (int i = 0; i < 4; ++i) {
        half8 kf = *(const half8*)(Ks + (i * 16 + c15) * 128 + koff);
        st[i] = __builtin_amdgcn_mfma_f32_16x16x32_f16(kf, qf[ks], st[i], 0, 0, 0);
      }
    }
    __builtin_amdgcn_s_setprio(0);

    // shift-free softmax: p = exp2(s)
    float ps0 = 0.f, ps1 = 0.f;
    unsigned int pu[8];
#pragma unroll
    for (int x = 0; x < 8; ++x) {
      float p0 = fast_exp2(st[x >> 1][(x & 1) * 2]);
      float p1 = fast_exp2(st[x >> 1][(x & 1) * 2 + 1]);
      ps0 += p0;
      ps1 += p1;
      pu[x] = pack2_f16(p0, p1);
    }
    lsum += ps0 + ps1;

    // P^T -> per-wave LDS strip [16 q][136B]
#pragma unroll
    for (int i = 0; i < 4; ++i) {
      union { unsigned int u[2]; uint2 v; } pk;
      pk.u[0] = pu[2 * i]; pk.u[1] = pu[2 * i + 1];
      *(uint2*)(Pw + 32 * i + 8 * g) = pk.v;
    }

    // O^T += V^T @ P^T : rows d (16df+4g+r), col q
    __builtin_amdgcn_s_setprio(1);
#pragma unroll
    for (int kb = 0; kb < 2; ++kb) {
      half8 pf = *(const half8*)(Pw + 64 * kb + 16 * g);
#pragma unroll
      for (int df = 0; df < 4; ++df)
        oacc[df] = __builtin_amdgcn_mfma_f32_16x16x32_f16(vfr[kb][df], pf, oacc[df], 0, 0, 0);
    }
    __builtin_amdgcn_s_setprio(0);
    __syncthreads();  // K(t+1) prefetch drained; Pw safe to reuse
    buf ^= 1;
  }

  // cross-g reduce of lsum
  lsum += __shfl_xor(lsum, 16, 64);
  lsum += __shfl_xor(lsum, 32, 64);
  float inv = 1.f / lsum;

  // transpose O^T through LDS, coalesced fp32 store
#pragma unroll
  for (int df = 0; df < 4; ++df) {
    floatx4 v = oacc[df] * inv;
    *(floatx4*)&Ot[(w * 16 + c15) * 68 + df * 16 + 4 * g] = v;
  }
  __syncthreads();
  int b = bh >> 4, h = bh & 15;
  int row = tid >> 2, seg = tid & 3;
  float* dstp = &out[((size_t)b * 2048 + q0 + row) * 1024 + h * 64 + seg * 16];
  const float* srcl = &Ot[row * 68 + seg * 16];
#pragma unroll
  for (int u = 0; u < 4; ++u)
    *(float4*)(dstp + u * 4) = *(const float4*)(srcl + u * 4);
}

// ---------------------------------------------------------------------------
extern "C" void kernel_launch(void* const* d_in, const int* in_sizes, int n_in,
                              void* d_out, int out_size, void* d_ws, size_t ws_size,
                              hipStream_t stream) {
  const float* xq = (const float*)d_in[0];
  const float* xk = (const float*)d_in[1];
  const float* wq = (const float*)d_in[2];
  const float* wk = (const float*)d_in[3];
  const float* wv = (const float*)d_in[4];
  char* ws = (char*)d_ws;
  f16* wqt = (f16*)(ws + (0ull << 20));
  f16* wkt = (f16*)(ws + (2ull << 20));
  f16* wvt = (f16*)(ws + (4ull << 20));
  f16* qbuf = (f16*)(ws + (6ull << 20));
  f16* kbuf = (f16*)(ws + (14ull << 20));
  f16* vtb  = (f16*)(ws + (22ull << 20));

  kwt<<<dim3(32, 32, 3), dim3(32, 8), 0, stream>>>(wq, wk, wv, wqt, wkt, wvt);
  kproj<<<dim3(8, 32, 3), 256, 0, stream>>>(xq, xk, wqt, wkt, wvt, qbuf, kbuf, vtb);
  kattn<<<1024, 256, 0, stream>>>(qbuf, kbuf, vtb, (float*)d_out);
}

// Round 8
// 144.532 us; speedup vs baseline: 1.3888x; 1.3888x over previous
//
#include <hip/hip_runtime.h>

#define DIN 1024
#define LSEQ 2048

typedef _Float16 f16;
typedef _Float16 half8 __attribute__((ext_vector_type(8)));
typedef float floatx4 __attribute__((ext_vector_type(4)));
typedef float floatx16 __attribute__((ext_vector_type(16)));

__device__ __forceinline__ void async_ld16(const void* g, void* l) {
  __builtin_amdgcn_global_load_lds(
      (const __attribute__((address_space(1))) void*)g,
      (__attribute__((address_space(3))) void*)l, 16, 0, 0);
}

__device__ __forceinline__ float fast_exp2(float x) {
#if __has_builtin(__builtin_amdgcn_exp2f)
  return __builtin_amdgcn_exp2f(x);
#else
  return exp2f(x);
#endif
}

__device__ __forceinline__ unsigned int pack2_f16(float a, float b) {
#if __has_builtin(__builtin_amdgcn_cvt_pkrtz)
  typedef __fp16 fp16x2 __attribute__((ext_vector_type(2)));
  fp16x2 h = __builtin_amdgcn_cvt_pkrtz(a, b);
  return __builtin_bit_cast(unsigned int, h);
#else
  union { f16 h[2]; unsigned int u; } pk;
  pk.h[0] = (f16)a; pk.h[1] = (f16)b;
  return pk.u;
#endif
}

// ---------------- Kernel 1: W [k][n] fp32 -> Wt [n][k] fp16 ----------------
__global__ void __launch_bounds__(256) kwt(const float* __restrict__ wq,
                                           const float* __restrict__ wk,
                                           const float* __restrict__ wv,
                                           f16* __restrict__ wqt,
                                           f16* __restrict__ wkt,
                                           f16* __restrict__ wvt) {
  __shared__ float t[32][33];
  const float* src = blockIdx.z == 0 ? wq : (blockIdx.z == 1 ? wk : wv);
  f16* dst = blockIdx.z == 0 ? wqt : (blockIdx.z == 1 ? wkt : wvt);
  int k0 = blockIdx.x * 32, n0 = blockIdx.y * 32;
  int tx = threadIdx.x, ty = threadIdx.y;  // (32,8)
#pragma unroll
  for (int r = 0; r < 4; ++r)
    t[ty + r * 8][tx] = src[(k0 + ty + r * 8) * DIN + n0 + tx];
  __syncthreads();
#pragma unroll
  for (int r = 0; r < 4; ++r)
    dst[(n0 + ty + r * 8) * DIN + k0 + tx] = (f16)t[tx][ty + r * 8];
}

// ------------- Kernel 2: C = X(4096x1024) @ W -> Q/K fp16, V^T fp16 --------
__global__ void __launch_bounds__(256) kproj(const float* __restrict__ xq,
                                             const float* __restrict__ xk,
                                             const f16* __restrict__ wqt,
                                             const f16* __restrict__ wkt,
                                             const f16* __restrict__ wvt,
                                             f16* __restrict__ qb,
                                             f16* __restrict__ kb,
                                             f16* __restrict__ vtb) {
  __shared__ __align__(16) char smem[34816];  // As 16K | Bs 16K ; z=2 epilogue
  char* As = smem;
  char* Bs = smem + 16384;
  const float* X;
  const f16* W;
  int z = blockIdx.z;
  if (z == 0) { X = xq; W = wqt; }
  else if (z == 1) { X = xk; W = wkt; }
  else { X = xk; W = wvt; }
  float oscale = (z == 0) ? 0.18033688011112042f : 1.0f;  // SC only for Q
  int m0 = blockIdx.y * 128, n0 = blockIdx.x * 128;
  int tid = threadIdx.x, lane = tid & 63, wid = tid >> 6;
  int wm = wid >> 1, wn = wid & 1;
  int c15 = lane & 15, g = lane >> 4;
  int l8 = lane >> 3, l7 = lane & 7;
  int kk = 8 * (l7 ^ l8);
  int swz = (c15 & 7) << 4;
  floatx4 acc[4][4] = {};

  for (int kt = 0; kt < 16; ++kt) {
    int k0 = kt * 64;
#pragma unroll
    for (int cc = 0; cc < 4; ++cc) {
      int c = wid * 4 + cc;
      async_ld16(&W[(n0 + c * 8 + l8) * DIN + k0 + kk], Bs + c * 1024);
    }
    {
      int q = tid & 15;
#pragma unroll
      for (int p = 0; p < 8; ++p) {
        int row = p * 16 + (tid >> 4);
        const float4 v = *(const float4*)&X[(m0 + row) * DIN + k0 + q * 4];
        union { unsigned int u[2]; uint2 v2; } pk;
        pk.u[0] = pack2_f16(v.x, v.y);
        pk.u[1] = pack2_f16(v.z, v.w);
        *(uint2*)(As + row * 128 + ((q * 8) ^ ((row & 7) << 4))) = pk.v2;
      }
    }
    __syncthreads();
#pragma unroll
    for (int ks = 0; ks < 2; ++ks) {
      int koff = (ks * 64 + g * 16) ^ swz;
      half8 af[4], bf[4];
#pragma unroll
      for (int i = 0; i < 4; ++i)
        af[i] = *(const half8*)(As + (wm * 64 + i * 16 + c15) * 128 + koff);
#pragma unroll
      for (int j = 0; j < 4; ++j)
        bf[j] = *(const half8*)(Bs + (wn * 64 + j * 16 + c15) * 128 + koff);
#pragma unroll
      for (int i = 0; i < 4; ++i)
#pragma unroll
        for (int j = 0; j < 4; ++j)
          acc[i][j] = __builtin_amdgcn_mfma_f32_16x16x32_f16(af[i], bf[j], acc[i][j], 0, 0, 0);
    }
    __syncthreads();
  }

  if (z != 2) {
    f16* dst = (z == 0) ? qb : kb;
#pragma unroll
    for (int i = 0; i < 4; ++i) {
      int mrow = m0 + wm * 64 + i * 16 + 4 * g;
#pragma unroll
      for (int j = 0; j < 4; ++j) {
        int n = n0 + wn * 64 + j * 16 + c15;
        int h = n >> 6, d = n & 63;
#pragma unroll
        for (int r = 0; r < 4; ++r) {
          int m = mrow + r;
          int b = m >> 11, lrow = m & 2047;
          dst[(((b << 4) + h) * 2048 + lrow) * 64 + d] = (f16)(acc[i][j][r] * oscale);
        }
      }
    }
  } else {
    // V^T epilogue: C^T f16 in LDS [128 n][272B], coalesced vtb rows.
#pragma unroll
    for (int i = 0; i < 4; ++i) {
      int mb = (wm * 64 + i * 16 + 4 * g) * 2;
#pragma unroll
      for (int j = 0; j < 4; ++j) {
        int nl = wn * 64 + j * 16 + c15;
        union { unsigned int u[2]; uint2 v; } pk;
        pk.u[0] = pack2_f16(acc[i][j][0], acc[i][j][1]);
        pk.u[1] = pack2_f16(acc[i][j][2], acc[i][j][3]);
        *(uint2*)(smem + nl * 272 + mb) = pk.v;
      }
    }
    __syncthreads();
    int rowp = tid >> 1, halfp = tid & 1;
    int n = n0 + rowp, h = n >> 6, d = n & 63;
    int b = m0 >> 11, lbase = m0 & 2047;
    f16* dstp = vtb + (((size_t)b * 16 + h) * 64 + d) * 2048 + lbase + halfp * 64;
    const char* srcl = smem + rowp * 272 + halfp * 128;
#pragma unroll
    for (int u = 0; u < 8; ++u)
      *(uint4*)(dstp + u * 8) = *(const uint4*)(srcl + u * 16);
  }
}

// --------------------- Kernel 3: flash attention ---------------------------
// 64 q/block, KV tile 64, K/V double-buffered LDS (identical staging to R4).
// NEW: mfma_f32_32x32x16_f16 -> same fragment bytes per MFMA but 2x MACs =>
// K/V LDS-read traffic per FLOP halves. Wave w = (qh=w&1, kvh=w>>1): computes
// S^T[32 kv][32 q] (4 MFMAs, k=64) and kv-partial O^T[64 d][32 q] (4 MFMAs);
// O/lsum cross-wave reduced once in the epilogue. Shift-free exp2 softmax.
// 32x32 frag maps: C/D col=lane&31, row=(reg&3)+8*(reg>>2)+4*(lane>>5);
// A/B row|col=lane&31, k=8*(lane>>5)+idx (contiguous 8k per lane).
__global__ void __launch_bounds__(256, 3) kattn(const f16* __restrict__ qb,
                                                const f16* __restrict__ kbuf,
                                                const f16* __restrict__ vt,
                                                float* __restrict__ out) {
  // [0,16384): K dbuf [64 kv][128B] xor ((row&7)<<4)
  // [16384,32768): V dbuf [64 d][128B kv] xor ((row&7)<<4)
  // [32768,41984): per-wave P strips [32 q][72B] (Q staging overlay)
  // [41984,42496): lsb [4 w][32 q] f32
  __shared__ __align__(16) char smem[42496];
  char* Qs = smem + 32768;
  char* Ps = smem + 32768;
  float* lsb = (float*)(smem + 41984);
  float* Ot = (float*)smem;  // epilogue overlay [64 q][68 d] f32 = 17408B

  // XCD swizzle: 4 heads per XCD -> K/V working set 2MB fits 4MB L2.
  int id = blockIdx.x;
  int wi = id >> 3;
  int bh = ((id & 7) << 2) | (wi >> 5);
  int q0 = (wi & 31) << 6;

  int tid = threadIdx.x, lane = tid & 63, w = tid >> 6;
  int qh = w & 1, kvh = w >> 1;
  int lane31 = lane & 31, h = lane >> 5;
  int l8 = lane >> 3, l7 = lane & 7;
  int kk = 8 * (l7 ^ l8);
  int rsw = (lane31 & 7) << 4;  // row&7 swizzle (rows == lane31 mod 8 here)

  const f16* kbase = kbuf + (size_t)bh * 2048 * 64;
  const f16* vbase = vt + (size_t)bh * 64 * 2048;

  auto stage = [&](int buf, int kv0) {
#pragma unroll
    for (int cc = 0; cc < 2; ++cc) {
      int c = w * 2 + cc;
      async_ld16(&kbase[(kv0 + c * 8 + l8) * 64 + kk], smem + buf * 8192 + c * 1024);
      async_ld16(&vbase[(c * 8 + l8) * 2048 + kv0 + kk],
                 smem + 16384 + buf * 8192 + c * 1024);
    }
  };

  // prologue: Q (8KB linear [64 q][128B]) + tile0
#pragma unroll
  for (int cc = 0; cc < 2; ++cc) {
    int c = w * 2 + cc;
    async_ld16(&qb[((size_t)bh * 2048 + q0 + c * 8 + l8) * 64 + kk], Qs + c * 1024);
  }
  stage(0, 0);
  __syncthreads();
  half8 qf[4];  // B-frags: col q = qh*32+lane31, k = 32*ksl..+8*(h)+idx
#pragma unroll
  for (int ksl = 0; ksl < 4; ++ksl)
    qf[ksl] = *(const half8*)(Qs + (qh * 32 + lane31) * 128 +
                              ((32 * ksl + 16 * h) ^ rsw));
  __syncthreads();  // qf reads done before P overlays Qs

  float lsum = 0.f;
  floatx16 oacc[2] = {};
  char* Pr = Ps + w * 2304 + lane31 * 72;

  int buf = 0;
  for (int t = 0; t < 32; ++t) {
    if (t < 31) stage(buf ^ 1, (t + 1) * 64);  // prefetch next tile
    const char* Ks = smem + buf * 8192;
    const char* Vs = smem + 16384 + buf * 8192;

    // S^T[kv=kvh*32+C-row][q=qh*32+lane31], contraction k=64 (4 slices)
    floatx16 st = {};
    __builtin_amdgcn_s_setprio(1);
#pragma unroll
    for (int ksl = 0; ksl < 4; ++ksl) {
      half8 kf = *(const half8*)(Ks + (kvh * 32 + lane31) * 128 +
                                 ((32 * ksl + 16 * h) ^ rsw));
      st = __builtin_amdgcn_mfma_f32_32x32x16_f16(kf, qf[ksl], st, 0, 0, 0);
    }
    __builtin_amdgcn_s_setprio(0);

    // shift-free softmax: p = exp2(s); word j covers kv 8*(j>>1)+4h+2*(j&1)+{0,1}
    float ps0 = 0.f, ps1 = 0.f;
    unsigned int pu[8];
#pragma unroll
    for (int i = 0; i < 8; ++i) {
      float p0 = fast_exp2(st[2 * i]);
      float p1 = fast_exp2(st[2 * i + 1]);
      ps0 += p0;
      ps1 += p1;
      pu[i] = pack2_f16(p0, p1);
    }
    lsum += ps0 + ps1;

    // P strip [32 q][72B], byte = 2*kv(within half): 4 b64 writes
#pragma unroll
    for (int i = 0; i < 4; ++i) {
      union { unsigned int u[2]; uint2 v; } pk;
      pk.u[0] = pu[2 * i]; pk.u[1] = pu[2 * i + 1];
      *(uint2*)(Pr + 16 * i + 8 * h) = pk.v;
    }

    // O^T[d][q] += V^T[d][kv-half] @ P
    __builtin_amdgcn_s_setprio(1);
#pragma unroll
    for (int kvsl = 0; kvsl < 2; ++kvsl) {
      half8 pf = *(const half8*)(Pr + 32 * kvsl + 16 * h);
#pragma unroll
      for (int dblk = 0; dblk < 2; ++dblk) {
        half8 vf = *(const half8*)(Vs + (dblk * 32 + lane31) * 128 +
                                   ((64 * kvh + 32 * kvsl + 16 * h) ^ rsw));
        oacc[dblk] = __builtin_amdgcn_mfma_f32_32x32x16_f16(vf, pf, oacc[dblk], 0, 0, 0);
      }
    }
    __builtin_amdgcn_s_setprio(0);
    __syncthreads();  // prefetch drained; P safe to rewrite
    buf ^= 1;
  }

  // lsum: partner lane (l^32) holds same q, other kv rows of this wave
  lsum += __shfl_xor(lsum, 32, 64);
  if (h == 0) lsb[w * 32 + lane31] = lsum;
  __syncthreads();  // all loop LDS reads done; K/V region free for Ot

  // O reduce: waves kvh==0 write, kvh==1 add. Ot[64 q][68 d].
  if (kvh == 0) {
#pragma unroll
    for (int dblk = 0; dblk < 2; ++dblk)
#pragma unroll
      for (int rg = 0; rg < 4; ++rg) {
        floatx4 v = {oacc[dblk][4 * rg], oacc[dblk][4 * rg + 1],
                     oacc[dblk][4 * rg + 2], oacc[dblk][4 * rg + 3]};
        *(floatx4*)&Ot[(qh * 32 + lane31) * 68 + dblk * 32 + 8 * rg + 4 * h] = v;
      }
  }
  __syncthreads();
  if (kvh == 1) {
#pragma unroll
    for (int dblk = 0; dblk < 2; ++dblk)
#pragma unroll
      for (int rg = 0; rg < 4; ++rg) {
        float* p = &Ot[(qh * 32 + lane31) * 68 + dblk * 32 + 8 * rg + 4 * h];
        floatx4 v = {oacc[dblk][4 * rg], oacc[dblk][4 * rg + 1],
                     oacc[dblk][4 * rg + 2], oacc[dblk][4 * rg + 3]};
        *(floatx4*)p = *(const floatx4*)p + v;
      }
  }
  __syncthreads();

  // normalize + coalesced store
  int b = bh >> 4, hh = bh & 15;
  int row = tid >> 2, seg = tid & 3;
  float lst = lsb[(row >> 5) * 32 + (row & 31)] +
              lsb[((row >> 5) + 2) * 32 + (row & 31)];
  float inv = 1.f / lst;
  float* dstp = &out[((size_t)b * 2048 + q0 + row) * 1024 + hh * 64 + seg * 16];
  const float* srcl = &Ot[row * 68 + seg * 16];
#pragma unroll
  for (int u = 0; u < 4; ++u) {
    floatx4 v = *(const floatx4*)(srcl + u * 4) * inv;
    *(floatx4*)(dstp + u * 4) = v;
  }
}

// ---------------------------------------------------------------------------
extern "C" void kernel_launch(void* const* d_in, const int* in_sizes, int n_in,
                              void* d_out, int out_size, void* d_ws, size_t ws_size,
                              hipStream_t stream) {
  const float* xq = (const float*)d_in[0];
  const float* xk = (const float*)d_in[1];
  const float* wq = (const float*)d_in[2];
  const float* wk = (const float*)d_in[3];
  const float* wv = (const float*)d_in[4];
  char* ws = (char*)d_ws;
  f16* wqt = (f16*)(ws + (0ull << 20));
  f16* wkt = (f16*)(ws + (2ull << 20));
  f16* wvt = (f16*)(ws + (4ull << 20));
  f16* qbuf = (f16*)(ws + (6ull << 20));
  f16* kbuf = (f16*)(ws + (14ull << 20));
  f16* vtb  = (f16*)(ws + (22ull << 20));

  kwt<<<dim3(32, 32, 3), dim3(32, 8), 0, stream>>>(wq, wk, wv, wqt, wkt, wvt);
  kproj<<<dim3(8, 32, 3), 256, 0, stream>>>(xq, xk, wqt, wkt, wvt, qbuf, kbuf, vtb);
  kattn<<<1024, 256, 0, stream>>>(qbuf, kbuf, vtb, (float*)d_out);
}

// Round 9
// 138.942 us; speedup vs baseline: 1.4447x; 1.0402x over previous
//
#include <hip/hip_runtime.h>

#define DIN 1024
#define LSEQ 2048

typedef _Float16 f16;
typedef _Float16 half8 __attribute__((ext_vector_type(8)));
typedef float floatx4 __attribute__((ext_vector_type(4)));

__device__ __forceinline__ void async_ld16(const void* g, void* l) {
  __builtin_amdgcn_global_load_lds(
      (const __attribute__((address_space(1))) void*)g,
      (__attribute__((address_space(3))) void*)l, 16, 0, 0);
}

__device__ __forceinline__ float fast_exp2(float x) {
#if __has_builtin(__builtin_amdgcn_exp2f)
  return __builtin_amdgcn_exp2f(x);
#else
  return exp2f(x);
#endif
}

__device__ __forceinline__ unsigned int pack2_f16(float a, float b) {
#if __has_builtin(__builtin_amdgcn_cvt_pkrtz)
  typedef __fp16 fp16x2 __attribute__((ext_vector_type(2)));
  fp16x2 h = __builtin_amdgcn_cvt_pkrtz(a, b);
  return __builtin_bit_cast(unsigned int, h);
#else
  union { f16 h[2]; unsigned int u; } pk;
  pk.h[0] = (f16)a; pk.h[1] = (f16)b;
  return pk.u;
#endif
}

// ---------------- Kernel 1: W [k][n] fp32 -> Wt [n][k] fp16 ----------------
__global__ void __launch_bounds__(256) kwt(const float* __restrict__ wq,
                                           const float* __restrict__ wk,
                                           const float* __restrict__ wv,
                                           f16* __restrict__ wqt,
                                           f16* __restrict__ wkt,
                                           f16* __restrict__ wvt) {
  __shared__ float t[32][33];
  const float* src = blockIdx.z == 0 ? wq : (blockIdx.z == 1 ? wk : wv);
  f16* dst = blockIdx.z == 0 ? wqt : (blockIdx.z == 1 ? wkt : wvt);
  int k0 = blockIdx.x * 32, n0 = blockIdx.y * 32;
  int tx = threadIdx.x, ty = threadIdx.y;  // (32,8)
#pragma unroll
  for (int r = 0; r < 4; ++r)
    t[ty + r * 8][tx] = src[(k0 + ty + r * 8) * DIN + n0 + tx];
  __syncthreads();
#pragma unroll
  for (int r = 0; r < 4; ++r)
    dst[(n0 + ty + r * 8) * DIN + k0 + tx] = (f16)t[tx][ty + r * 8];
}

// ------------- Kernel 2: C = X(4096x1024) @ W -> Q/K fp16, V^T fp16 --------
__global__ void __launch_bounds__(256) kproj(const float* __restrict__ xq,
                                             const float* __restrict__ xk,
                                             const f16* __restrict__ wqt,
                                             const f16* __restrict__ wkt,
                                             const f16* __restrict__ wvt,
                                             f16* __restrict__ qb,
                                             f16* __restrict__ kb,
                                             f16* __restrict__ vtb) {
  __shared__ __align__(16) char smem[34816];  // As 16K | Bs 16K ; z=2 epilogue
  char* As = smem;
  char* Bs = smem + 16384;
  const float* X;
  const f16* W;
  int z = blockIdx.z;
  if (z == 0) { X = xq; W = wqt; }
  else if (z == 1) { X = xk; W = wkt; }
  else { X = xk; W = wvt; }
  float oscale = (z == 0) ? 0.18033688011112042f : 1.0f;  // SC only for Q
  int m0 = blockIdx.y * 128, n0 = blockIdx.x * 128;
  int tid = threadIdx.x, lane = tid & 63, wid = tid >> 6;
  int wm = wid >> 1, wn = wid & 1;
  int c15 = lane & 15, g = lane >> 4;
  int l8 = lane >> 3, l7 = lane & 7;
  int kk = 8 * (l7 ^ l8);
  int swz = (c15 & 7) << 4;
  floatx4 acc[4][4] = {};

  for (int kt = 0; kt < 16; ++kt) {
    int k0 = kt * 64;
#pragma unroll
    for (int cc = 0; cc < 4; ++cc) {
      int c = wid * 4 + cc;
      async_ld16(&W[(n0 + c * 8 + l8) * DIN + k0 + kk], Bs + c * 1024);
    }
    {
      int q = tid & 15;
#pragma unroll
      for (int p = 0; p < 8; ++p) {
        int row = p * 16 + (tid >> 4);
        const float4 v = *(const float4*)&X[(m0 + row) * DIN + k0 + q * 4];
        union { unsigned int u[2]; uint2 v2; } pk;
        pk.u[0] = pack2_f16(v.x, v.y);
        pk.u[1] = pack2_f16(v.z, v.w);
        *(uint2*)(As + row * 128 + ((q * 8) ^ ((row & 7) << 4))) = pk.v2;
      }
    }
    __syncthreads();
#pragma unroll
    for (int ks = 0; ks < 2; ++ks) {
      int koff = (ks * 64 + g * 16) ^ swz;
      half8 af[4], bf[4];
#pragma unroll
      for (int i = 0; i < 4; ++i)
        af[i] = *(const half8*)(As + (wm * 64 + i * 16 + c15) * 128 + koff);
#pragma unroll
      for (int j = 0; j < 4; ++j)
        bf[j] = *(const half8*)(Bs + (wn * 64 + j * 16 + c15) * 128 + koff);
#pragma unroll
      for (int i = 0; i < 4; ++i)
#pragma unroll
        for (int j = 0; j < 4; ++j)
          acc[i][j] = __builtin_amdgcn_mfma_f32_16x16x32_f16(af[i], bf[j], acc[i][j], 0, 0, 0);
    }
    __syncthreads();
  }

  if (z != 2) {
    f16* dst = (z == 0) ? qb : kb;
#pragma unroll
    for (int i = 0; i < 4; ++i) {
      int mrow = m0 + wm * 64 + i * 16 + 4 * g;
#pragma unroll
      for (int j = 0; j < 4; ++j) {
        int n = n0 + wn * 64 + j * 16 + c15;
        int h = n >> 6, d = n & 63;
#pragma unroll
        for (int r = 0; r < 4; ++r) {
          int m = mrow + r;
          int b = m >> 11, lrow = m & 2047;
          dst[(((b << 4) + h) * 2048 + lrow) * 64 + d] = (f16)(acc[i][j][r] * oscale);
        }
      }
    }
  } else {
    // V^T epilogue: C^T f16 in LDS [128 n][272B], coalesced vtb rows.
#pragma unroll
    for (int i = 0; i < 4; ++i) {
      int mb = (wm * 64 + i * 16 + 4 * g) * 2;
#pragma unroll
      for (int j = 0; j < 4; ++j) {
        int nl = wn * 64 + j * 16 + c15;
        union { unsigned int u[2]; uint2 v; } pk;
        pk.u[0] = pack2_f16(acc[i][j][0], acc[i][j][1]);
        pk.u[1] = pack2_f16(acc[i][j][2], acc[i][j][3]);
        *(uint2*)(smem + nl * 272 + mb) = pk.v;
      }
    }
    __syncthreads();
    int rowp = tid >> 1, halfp = tid & 1;
    int n = n0 + rowp, h = n >> 6, d = n & 63;
    int b = m0 >> 11, lbase = m0 & 2047;
    f16* dstp = vtb + (((size_t)b * 16 + h) * 64 + d) * 2048 + lbase + halfp * 64;
    const char* srcl = smem + rowp * 272 + halfp * 128;
#pragma unroll
    for (int u = 0; u < 8; ++u)
      *(uint4*)(dstp + u * 8) = *(const uint4*)(srcl + u * 16);
  }
}

// --------------------- Kernel 3: flash attention ---------------------------
// R4 structure (16x16x32 MFMA, 64 q/block, KV tile 64) but K and V SINGLE-
// buffered with a 2-barrier pipeline -> LDS 25KB -> 6 blocks/CU (24 waves,
// 2.9x R4). Staging windows:
//   QK(t) | BAR1 | issue K(t+1); softmax; PV(t) | BAR2 | issue V(t+1)
// BAR1 drains V(t) (issued after prev BAR2); BAR2 drains K(t+1). Each stage
// has a half-tile of compute+barrier to land. Shift-free exp2 softmax.
__global__ void __launch_bounds__(256, 6) kattn(const f16* __restrict__ qb,
                                                const f16* __restrict__ kbuf,
                                                const f16* __restrict__ vt,
                                                float* __restrict__ out) {
  // [0,8192): K [64 kv][128B]   [8192,16384): V [64 d][128B kv]
  // [16384,25088): per-wave P strips [16 q][136B] (Q staging overlay)
  __shared__ __align__(16) char smem[25088];
  char* Qs = smem + 16384;
  float* Ot = (float*)smem;  // epilogue overlay [64][68] f32 = 17408B

  // XCD swizzle: 4 heads per XCD -> K/V working set 2MB fits 4MB L2.
  int id = blockIdx.x;
  int wi = id >> 3;
  int bh = ((id & 7) << 2) | (wi >> 5);
  int q0 = (wi & 31) << 6;

  int tid = threadIdx.x, lane = tid & 63, w = tid >> 6;
  int c15 = lane & 15, g = lane >> 4;
  int l8 = lane >> 3, l7 = lane & 7;
  int kk = 8 * (l7 ^ l8);
  int swz = (c15 & 7) << 4;

  const f16* kbase = kbuf + (size_t)bh * 2048 * 64;
  const f16* vbase = vt + (size_t)bh * 64 * 2048;

  auto stageK = [&](int kv0) {
#pragma unroll
    for (int cc = 0; cc < 2; ++cc) {
      int c = w * 2 + cc;
      async_ld16(&kbase[(kv0 + c * 8 + l8) * 64 + kk], smem + c * 1024);
    }
  };
  auto stageV = [&](int kv0) {
#pragma unroll
    for (int cc = 0; cc < 2; ++cc) {
      int c = w * 2 + cc;
      async_ld16(&vbase[(c * 8 + l8) * 2048 + kv0 + kk], smem + 8192 + c * 1024);
    }
  };

  // prologue: Q + K(0) + V(0)
#pragma unroll
  for (int cc = 0; cc < 2; ++cc) {
    int c = w * 2 + cc;
    async_ld16(&qb[((size_t)bh * 2048 + q0 + c * 8 + l8) * 64 + kk],
               Qs + c * 1024);
  }
  stageK(0);
  stageV(0);
  __syncthreads();
  half8 qf[2];
#pragma unroll
  for (int ks = 0; ks < 2; ++ks)
    qf[ks] = *(const half8*)(Qs + (w * 16 + c15) * 128 + ((ks * 64 + g * 16) ^ swz));
  __syncthreads();  // qf reads done before P overlays Qs

  float lsum = 0.f;
  floatx4 oacc[4] = {};
  char* Pw = smem + 16384 + w * 2176 + c15 * 136;

  for (int t = 0; t < 32; ++t) {
    // ---- QK(t): S^T = K @ Q^T, rows kv (16i+4g+r), col q (w*16+c15) ----
    floatx4 st[4] = {};
    __builtin_amdgcn_s_setprio(1);
#pragma unroll
    for (int ks = 0; ks < 2; ++ks) {
      int koff = (ks * 64 + g * 16) ^ swz;
#pragma unroll
      for (int i = 0; i < 4; ++i) {
        half8 kf = *(const half8*)(smem + (i * 16 + c15) * 128 + koff);
        st[i] = __builtin_amdgcn_mfma_f32_16x16x32_f16(kf, qf[ks], st[i], 0, 0, 0);
      }
    }
    __builtin_amdgcn_s_setprio(0);
    __syncthreads();  // BAR1: K(t) reads done by all; V(t) loads drained
    if (t < 31) stageK((t + 1) * 64);  // lands during softmax+PV, drained @BAR2

    // ---- shift-free softmax: p = exp2(s) ----
    float ps0 = 0.f, ps1 = 0.f;
    unsigned int pu[8];
#pragma unroll
    for (int x = 0; x < 8; ++x) {
      float p0 = fast_exp2(st[x >> 1][(x & 1) * 2]);
      float p1 = fast_exp2(st[x >> 1][(x & 1) * 2 + 1]);
      ps0 += p0;
      ps1 += p1;
      pu[x] = pack2_f16(p0, p1);
    }
    lsum += ps0 + ps1;

    // P^T -> per-wave LDS strip [16 q][136B]
#pragma unroll
    for (int i = 0; i < 4; ++i) {
      union { unsigned int u[2]; uint2 v; } pk;
      pk.u[0] = pu[2 * i]; pk.u[1] = pu[2 * i + 1];
      *(uint2*)(Pw + 32 * i + 8 * g) = pk.v;
    }

    // ---- PV(t): O^T += V^T @ P^T, rows d (16df+4g+r), col q ----
    __builtin_amdgcn_s_setprio(1);
#pragma unroll
    for (int kb = 0; kb < 2; ++kb) {
      half8 pf = *(const half8*)(Pw + 64 * kb + 16 * g);
      int koff = (kb * 64 + g * 16) ^ swz;
#pragma unroll
      for (int df = 0; df < 4; ++df) {
        half8 vf = *(const half8*)(smem + 8192 + (df * 16 + c15) * 128 + koff);
        oacc[df] = __builtin_amdgcn_mfma_f32_16x16x32_f16(vf, pf, oacc[df], 0, 0, 0);
      }
    }
    __builtin_amdgcn_s_setprio(0);
    __syncthreads();  // BAR2: V(t) reads done by all; K(t+1) loads drained
    if (t < 31) stageV((t + 1) * 64);  // lands during next QK, drained @BAR1
  }

  // cross-g reduce of lsum
  lsum += __shfl_xor(lsum, 16, 64);
  lsum += __shfl_xor(lsum, 32, 64);
  float inv = 1.f / lsum;

  // transpose O^T through LDS, coalesced fp32 store
#pragma unroll
  for (int df = 0; df < 4; ++df) {
    floatx4 v = oacc[df] * inv;
    *(floatx4*)&Ot[(w * 16 + c15) * 68 + df * 16 + 4 * g] = v;
  }
  __syncthreads();
  int b = bh >> 4, h = bh & 15;
  int row = tid >> 2, seg = tid & 3;
  float* dstp = &out[((size_t)b * 2048 + q0 + row) * 1024 + h * 64 + seg * 16];
  const float* srcl = &Ot[row * 68 + seg * 16];
#pragma unroll
  for (int u = 0; u < 4; ++u)
    *(float4*)(dstp + u * 4) = *(const float4*)(srcl + u * 4);
}

// ---------------------------------------------------------------------------
extern "C" void kernel_launch(void* const* d_in, const int* in_sizes, int n_in,
                              void* d_out, int out_size, void* d_ws, size_t ws_size,
                              hipStream_t stream) {
  const float* xq = (const float*)d_in[0];
  const float* xk = (const float*)d_in[1];
  const float* wq = (const float*)d_in[2];
  const float* wk = (const float*)d_in[3];
  const float* wv = (const float*)d_in[4];
  char* ws = (char*)d_ws;
  f16* wqt = (f16*)(ws + (0ull << 20));
  f16* wkt = (f16*)(ws + (2ull << 20));
  f16* wvt = (f16*)(ws + (4ull << 20));
  f16* qbuf = (f16*)(ws + (6ull << 20));
  f16* kbuf = (f16*)(ws + (14ull << 20));
  f16* vtb  = (f16*)(ws + (22ull << 20));

  kwt<<<dim3(32, 32, 3), dim3(32, 8), 0, stream>>>(wq, wk, wv, wqt, wkt, wvt);
  kproj<<<dim3(8, 32, 3), 256, 0, stream>>>(xq, xk, wqt, wkt, wvt, qbuf, kbuf, vtb);
  kattn<<<1024, 256, 0, stream>>>(qbuf, kbuf, vtb, (float*)d_out);
}

// Round 10
// 138.336 us; speedup vs baseline: 1.4510x; 1.0044x over previous
//
#include <hip/hip_runtime.h>

#define DIN 1024
#define LSEQ 2048

typedef _Float16 f16;
typedef _Float16 half8 __attribute__((ext_vector_type(8)));
typedef float floatx4 __attribute__((ext_vector_type(4)));

__device__ __forceinline__ void async_ld16(const void* g, void* l) {
  __builtin_amdgcn_global_load_lds(
      (const __attribute__((address_space(1))) void*)g,
      (__attribute__((address_space(3))) void*)l, 16, 0, 0);
}

__device__ __forceinline__ float fast_exp2(float x) {
#if __has_builtin(__builtin_amdgcn_exp2f)
  return __builtin_amdgcn_exp2f(x);
#else
  return exp2f(x);
#endif
}

__device__ __forceinline__ unsigned int pack2_f16(float a, float b) {
#if __has_builtin(__builtin_amdgcn_cvt_pkrtz)
  typedef __fp16 fp16x2 __attribute__((ext_vector_type(2)));
  fp16x2 h = __builtin_amdgcn_cvt_pkrtz(a, b);
  return __builtin_bit_cast(unsigned int, h);
#else
  union { f16 h[2]; unsigned int u; } pk;
  pk.h[0] = (f16)a; pk.h[1] = (f16)b;
  return pk.u;
#endif
}

// ---------------- Kernel 1: W [k][n] fp32 -> Wt [n][k] fp16 ----------------
__global__ void __launch_bounds__(256) kwt(const float* __restrict__ wq,
                                           const float* __restrict__ wk,
                                           const float* __restrict__ wv,
                                           f16* __restrict__ wqt,
                                           f16* __restrict__ wkt,
                                           f16* __restrict__ wvt) {
  __shared__ float t[32][33];
  const float* src = blockIdx.z == 0 ? wq : (blockIdx.z == 1 ? wk : wv);
  f16* dst = blockIdx.z == 0 ? wqt : (blockIdx.z == 1 ? wkt : wvt);
  int k0 = blockIdx.x * 32, n0 = blockIdx.y * 32;
  int tx = threadIdx.x, ty = threadIdx.y;  // (32,8)
#pragma unroll
  for (int r = 0; r < 4; ++r)
    t[ty + r * 8][tx] = src[(k0 + ty + r * 8) * DIN + n0 + tx];
  __syncthreads();
#pragma unroll
  for (int r = 0; r < 4; ++r)
    dst[(n0 + ty + r * 8) * DIN + k0 + tx] = (f16)t[tx][ty + r * 8];
}

// ------------- Kernel 2: C = X(4096x1024) @ W -> Q/K fp16, V^T fp16 --------
__global__ void __launch_bounds__(256) kproj(const float* __restrict__ xq,
                                             const float* __restrict__ xk,
                                             const f16* __restrict__ wqt,
                                             const f16* __restrict__ wkt,
                                             const f16* __restrict__ wvt,
                                             f16* __restrict__ qb,
                                             f16* __restrict__ kb,
                                             f16* __restrict__ vtb) {
  __shared__ __align__(16) char smem[34816];  // As 16K | Bs 16K ; z=2 epilogue
  char* As = smem;
  char* Bs = smem + 16384;
  const float* X;
  const f16* W;
  int z = blockIdx.z;
  if (z == 0) { X = xq; W = wqt; }
  else if (z == 1) { X = xk; W = wkt; }
  else { X = xk; W = wvt; }
  float oscale = (z == 0) ? 0.18033688011112042f : 1.0f;  // SC only for Q
  int m0 = blockIdx.y * 128, n0 = blockIdx.x * 128;
  int tid = threadIdx.x, lane = tid & 63, wid = tid >> 6;
  int wm = wid >> 1, wn = wid & 1;
  int c15 = lane & 15, g = lane >> 4;
  int l8 = lane >> 3, l7 = lane & 7;
  int kk = 8 * (l7 ^ l8);
  int swz = (c15 & 7) << 4;
  floatx4 acc[4][4] = {};

  for (int kt = 0; kt < 16; ++kt) {
    int k0 = kt * 64;
#pragma unroll
    for (int cc = 0; cc < 4; ++cc) {
      int c = wid * 4 + cc;
      async_ld16(&W[(n0 + c * 8 + l8) * DIN + k0 + kk], Bs + c * 1024);
    }
    {
      int q = tid & 15;
#pragma unroll
      for (int p = 0; p < 8; ++p) {
        int row = p * 16 + (tid >> 4);
        const float4 v = *(const float4*)&X[(m0 + row) * DIN + k0 + q * 4];
        union { unsigned int u[2]; uint2 v2; } pk;
        pk.u[0] = pack2_f16(v.x, v.y);
        pk.u[1] = pack2_f16(v.z, v.w);
        *(uint2*)(As + row * 128 + ((q * 8) ^ ((row & 7) << 4))) = pk.v2;
      }
    }
    __syncthreads();
#pragma unroll
    for (int ks = 0; ks < 2; ++ks) {
      int koff = (ks * 64 + g * 16) ^ swz;
      half8 af[4], bf[4];
#pragma unroll
      for (int i = 0; i < 4; ++i)
        af[i] = *(const half8*)(As + (wm * 64 + i * 16 + c15) * 128 + koff);
#pragma unroll
      for (int j = 0; j < 4; ++j)
        bf[j] = *(const half8*)(Bs + (wn * 64 + j * 16 + c15) * 128 + koff);
#pragma unroll
      for (int i = 0; i < 4; ++i)
#pragma unroll
        for (int j = 0; j < 4; ++j)
          acc[i][j] = __builtin_amdgcn_mfma_f32_16x16x32_f16(af[i], bf[j], acc[i][j], 0, 0, 0);
    }
    __syncthreads();
  }

  if (z != 2) {
    f16* dst = (z == 0) ? qb : kb;
#pragma unroll
    for (int i = 0; i < 4; ++i) {
      int mrow = m0 + wm * 64 + i * 16 + 4 * g;
#pragma unroll
      for (int j = 0; j < 4; ++j) {
        int n = n0 + wn * 64 + j * 16 + c15;
        int h = n >> 6, d = n & 63;
#pragma unroll
        for (int r = 0; r < 4; ++r) {
          int m = mrow + r;
          int b = m >> 11, lrow = m & 2047;
          dst[(((b << 4) + h) * 2048 + lrow) * 64 + d] = (f16)(acc[i][j][r] * oscale);
        }
      }
    }
  } else {
    // V^T epilogue: C^T f16 in LDS [128 n][272B], coalesced vtb rows.
#pragma unroll
    for (int i = 0; i < 4; ++i) {
      int mb = (wm * 64 + i * 16 + 4 * g) * 2;
#pragma unroll
      for (int j = 0; j < 4; ++j) {
        int nl = wn * 64 + j * 16 + c15;
        union { unsigned int u[2]; uint2 v; } pk;
        pk.u[0] = pack2_f16(acc[i][j][0], acc[i][j][1]);
        pk.u[1] = pack2_f16(acc[i][j][2], acc[i][j][3]);
        *(uint2*)(smem + nl * 272 + mb) = pk.v;
      }
    }
    __syncthreads();
    int rowp = tid >> 1, halfp = tid & 1;
    int n = n0 + rowp, h = n >> 6, d = n & 63;
    int b = m0 >> 11, lbase = m0 & 2047;
    f16* dstp = vtb + (((size_t)b * 16 + h) * 64 + d) * 2048 + lbase + halfp * 64;
    const char* srcl = smem + rowp * 272 + halfp * 128;
#pragma unroll
    for (int u = 0; u < 8; ++u)
      *(uint4*)(dstp + u * 8) = *(const uint4*)(srcl + u * 16);
  }
}

// --------------------- Kernel 3: flash attention ---------------------------
// 128-thread blocks (2 waves), 64 q/block, 2 q-sets per wave (32 q/wave):
// each K-frag and V-frag LDS read feeds TWO MFMAs -> DS-pipe traffic per
// FLOP ~0.6x of R9, while grid stays 1024 (4 blocks/CU supply) and LDS
// stays 25KB (6 blocks/CU capacity, 12 resident waves). K and V single-
// buffered with the R9 2-barrier pipeline:
//   QK(t) | BAR1 | stage K(t+1); softmax; PV(t) | BAR2 | stage V(t+1)
// Shift-free exp2-domain softmax (Q pre-scaled in kproj).
__global__ void __launch_bounds__(128, 3) kattn(const f16* __restrict__ qb,
                                                const f16* __restrict__ kbuf,
                                                const f16* __restrict__ vt,
                                                float* __restrict__ out) {
  // [0,8192): K [64 kv][128B] xor((row&7)<<4)
  // [8192,16384): V [64 d][128B kv] xor((row&7)<<4)
  // [16384,25088): per-wave P strips [32 q][136B] (Q staging overlay)
  __shared__ __align__(16) char smem[25088];
  char* Qs = smem + 16384;
  float* Ot = (float*)smem;  // epilogue overlay [64 q][68 d] f32 = 17408B

  // XCD swizzle: 4 heads per XCD -> K/V working set 2MB fits 4MB L2.
  int id = blockIdx.x;
  int wi = id >> 3;
  int bh = ((id & 7) << 2) | (wi >> 5);
  int q0 = (wi & 31) << 6;

  int tid = threadIdx.x, lane = tid & 63, w = tid >> 6;  // w in {0,1}
  int c15 = lane & 15, g = lane >> 4;
  int l8 = lane >> 3, l7 = lane & 7;
  int kk = 8 * (l7 ^ l8);
  int swz = (c15 & 7) << 4;

  const f16* kbase = kbuf + (size_t)bh * 2048 * 64;
  const f16* vbase = vt + (size_t)bh * 64 * 2048;

  auto stageK = [&](int kv0) {  // 8 chunks, 4 per wave
#pragma unroll
    for (int cc = 0; cc < 4; ++cc) {
      int c = w * 4 + cc;
      async_ld16(&kbase[(kv0 + c * 8 + l8) * 64 + kk], smem + c * 1024);
    }
  };
  auto stageV = [&](int kv0) {
#pragma unroll
    for (int cc = 0; cc < 4; ++cc) {
      int c = w * 4 + cc;
      async_ld16(&vbase[(c * 8 + l8) * 2048 + kv0 + kk], smem + 8192 + c * 1024);
    }
  };

  // prologue: Q (8KB) + K(0) + V(0)
#pragma unroll
  for (int cc = 0; cc < 4; ++cc) {
    int c = w * 4 + cc;
    async_ld16(&qb[((size_t)bh * 2048 + q0 + c * 8 + l8) * 64 + kk],
               Qs + c * 1024);
  }
  stageK(0);
  stageV(0);
  __syncthreads();
  half8 qf[2][2];  // [q-set][k-slice]; wave w owns q rows w*32..w*32+31
#pragma unroll
  for (int s = 0; s < 2; ++s)
#pragma unroll
    for (int ks = 0; ks < 2; ++ks)
      qf[s][ks] = *(const half8*)(Qs + (w * 32 + s * 16 + c15) * 128 +
                                  ((ks * 64 + g * 16) ^ swz));
  __syncthreads();  // qf reads done before P overlays Qs

  float ls0 = 0.f, ls1 = 0.f;
  floatx4 oacc[2][4] = {};
  char* Pw = smem + 16384 + w * 4352;  // [32 q][136B]

  for (int t = 0; t < 32; ++t) {
    // ---- QK(t): S^T rows kv (16i+4g+r), cols q (w*32+s*16+c15) ----
    floatx4 st[2][4] = {};
    __builtin_amdgcn_s_setprio(1);
#pragma unroll
    for (int ks = 0; ks < 2; ++ks) {
      int koff = (ks * 64 + g * 16) ^ swz;
#pragma unroll
      for (int i = 0; i < 4; ++i) {
        half8 kf = *(const half8*)(smem + (i * 16 + c15) * 128 + koff);
        st[0][i] = __builtin_amdgcn_mfma_f32_16x16x32_f16(kf, qf[0][ks], st[0][i], 0, 0, 0);
        st[1][i] = __builtin_amdgcn_mfma_f32_16x16x32_f16(kf, qf[1][ks], st[1][i], 0, 0, 0);
      }
    }
    __builtin_amdgcn_s_setprio(0);
    __syncthreads();  // BAR1: K(t) reads done; V(t) loads drained
    if (t < 31) stageK((t + 1) * 64);  // lands during softmax+PV

    // ---- shift-free softmax: p = exp2(s), per q-set ----
    unsigned int pu[2][8];
#pragma unroll
    for (int s = 0; s < 2; ++s) {
      float ps0 = 0.f, ps1 = 0.f;
#pragma unroll
      for (int x = 0; x < 8; ++x) {
        float p0 = fast_exp2(st[s][x >> 1][(x & 1) * 2]);
        float p1 = fast_exp2(st[s][x >> 1][(x & 1) * 2 + 1]);
        ps0 += p0;
        ps1 += p1;
        pu[s][x] = pack2_f16(p0, p1);
      }
      if (s == 0) ls0 += ps0 + ps1; else ls1 += ps0 + ps1;
    }

    // P^T -> per-wave strip [32 q][136B]
#pragma unroll
    for (int s = 0; s < 2; ++s)
#pragma unroll
      for (int i = 0; i < 4; ++i) {
        union { unsigned int u[2]; uint2 v; } pk;
        pk.u[0] = pu[s][2 * i]; pk.u[1] = pu[s][2 * i + 1];
        *(uint2*)(Pw + (s * 16 + c15) * 136 + 32 * i + 8 * g) = pk.v;
      }

    // ---- PV(t): O^T rows d (16df+4g+r); vf shared across q-sets ----
    __builtin_amdgcn_s_setprio(1);
#pragma unroll
    for (int kb = 0; kb < 2; ++kb) {
      int koff = (kb * 64 + g * 16) ^ swz;
      half8 pf0 = *(const half8*)(Pw + (0 + c15) * 136 + kb * 64 + 16 * g);
      half8 pf1 = *(const half8*)(Pw + (16 + c15) * 136 + kb * 64 + 16 * g);
#pragma unroll
      for (int df = 0; df < 4; ++df) {
        half8 vf = *(const half8*)(smem + 8192 + (df * 16 + c15) * 128 + koff);
        oacc[0][df] = __builtin_amdgcn_mfma_f32_16x16x32_f16(vf, pf0, oacc[0][df], 0, 0, 0);
        oacc[1][df] = __builtin_amdgcn_mfma_f32_16x16x32_f16(vf, pf1, oacc[1][df], 0, 0, 0);
      }
    }
    __builtin_amdgcn_s_setprio(0);
    __syncthreads();  // BAR2: V(t) reads done; K(t+1) loads drained
    if (t < 31) stageV((t + 1) * 64);  // lands during next QK
  }

  // cross-g reduce of lsums
  ls0 += __shfl_xor(ls0, 16, 64);
  ls0 += __shfl_xor(ls0, 32, 64);
  ls1 += __shfl_xor(ls1, 16, 64);
  ls1 += __shfl_xor(ls1, 32, 64);
  float inv0 = 1.f / ls0, inv1 = 1.f / ls1;

  // transpose O^T through LDS, coalesced fp32 store
#pragma unroll
  for (int s = 0; s < 2; ++s) {
    float inv = s == 0 ? inv0 : inv1;
#pragma unroll
    for (int df = 0; df < 4; ++df) {
      floatx4 v = oacc[s][df] * inv;
      *(floatx4*)&Ot[(w * 32 + s * 16 + c15) * 68 + df * 16 + 4 * g] = v;
    }
  }
  __syncthreads();
  int b = bh >> 4, h = bh & 15;
  int row = tid >> 1, seg = tid & 1;  // 2 threads/row, 32 floats each
  float* dstp = &out[((size_t)b * 2048 + q0 + row) * 1024 + h * 64 + seg * 32];
  const float* srcl = &Ot[row * 68 + seg * 32];
#pragma unroll
  for (int u = 0; u < 8; ++u)
    *(float4*)(dstp + u * 4) = *(const float4*)(srcl + u * 4);
}

// ---------------------------------------------------------------------------
extern "C" void kernel_launch(void* const* d_in, const int* in_sizes, int n_in,
                              void* d_out, int out_size, void* d_ws, size_t ws_size,
                              hipStream_t stream) {
  const float* xq = (const float*)d_in[0];
  const float* xk = (const float*)d_in[1];
  const float* wq = (const float*)d_in[2];
  const float* wk = (const float*)d_in[3];
  const float* wv = (const float*)d_in[4];
  char* ws = (char*)d_ws;
  f16* wqt = (f16*)(ws + (0ull << 20));
  f16* wkt = (f16*)(ws + (2ull << 20));
  f16* wvt = (f16*)(ws + (4ull << 20));
  f16* qbuf = (f16*)(ws + (6ull << 20));
  f16* kbuf = (f16*)(ws + (14ull << 20));
  f16* vtb  = (f16*)(ws + (22ull << 20));

  kwt<<<dim3(32, 32, 3), dim3(32, 8), 0, stream>>>(wq, wk, wv, wqt, wkt, wvt);
  kproj<<<dim3(8, 32, 3), 256, 0, stream>>>(xq, xk, wqt, wkt, wvt, qbuf, kbuf, vtb);
  kattn<<<1024, 128, 0, stream>>>(qbuf, kbuf, vtb, (float*)d_out);
}